// Round 2
// 221.014 us; speedup vs baseline: 1.0101x; 1.0101x over previous
//
#include <hip/hip_runtime.h>

// HungarianCELoss — analytic collapse of the 120-perm matching.
// targets has only 2 distinct rows (fg, bg=1-fg) => argmin over perms ==
// argmin_k (cost_fg[k]-cost_bg[k]), ties -> smallest k (lex order of perms).
// Per-element identities (x = slot logit, fg = target):
//   d  = softplus(x) - x = log1p(exp(-|x|)) + max(-x,0);  sigmoid(x) = exp(-d)
//   sum_k A_k = sum d (all k,n) + sum_k XF_k,  C_k = 2*XF_k - X_k
//   answer = [sum_k A_k - C_{k*}] summed over b, / (B*K*N)
//
// R6 (= R5 with compile fix): block = (b, segment) across ALL k planes.
// The target float4 is read ONCE and consumed by 5 slot float4s in
// registers — cuts streamed traffic from 262 MB (target re-read per k) to
// the 157 MB minimum. Loads are nontemporal (strictly single-use; don't
// churn L2/L3). __builtin_nontemporal_load needs a native vector type, not
// HIP's float4 struct — use ext_vector_type(4).

#define BB 64
#define KK 5
#define NPIX 102400              // 320*320
#define Q 20                     // segments per (b) plane
#define SEG (NPIX / Q)           // 5120 floats = 20 KB
#define THREADS 256
#define ITERS (SEG / (THREADS * 4))   // 5 float4-iterations per thread
#define REC 32                   // floats per (b,q) record; 26 used
#define NVAL 26                  // 5 stats x 5 k + Tf
#define NBLK (BB * Q)            // 1280 blocks

typedef float f4 __attribute__((ext_vector_type(4)));

__global__ void hung_pass1(const float* __restrict__ slot,   // (B,K,N)
                           const float* __restrict__ tgt,    // (B,1,N)
                           float* __restrict__ ws)           // (NBLK, REC)
{
    const int bid = blockIdx.x;          // b*Q + q
    const int b   = bid / Q;
    const int q   = bid - b * Q;

    const float* sb = slot + (size_t)b * KK * NPIX + q * SEG;
    const float* t  = tgt  + (size_t)b * NPIX      + q * SEG;

    float aX[KK]  = {0,0,0,0,0};
    float aXF[KK] = {0,0,0,0,0};
    float aS[KK]  = {0,0,0,0,0};
    float aSF[KK] = {0,0,0,0,0};
    float aPX[KK] = {0,0,0,0,0};
    float Tf = 0.f;

    const int base = threadIdx.x * 4;
    #pragma unroll
    for (int i = 0; i < ITERS; ++i) {
        const int off = base + i * (THREADS * 4);
        const f4 fg4 = __builtin_nontemporal_load(
            reinterpret_cast<const f4*>(t + off));
        f4 x4[KK];
        #pragma unroll
        for (int k = 0; k < KK; ++k)
            x4[k] = __builtin_nontemporal_load(
                reinterpret_cast<const f4*>(sb + (size_t)k * NPIX + off));

        Tf += (fg4.x + fg4.y) + (fg4.z + fg4.w);

        #pragma unroll
        for (int k = 0; k < KK; ++k) {
            #pragma unroll
            for (int j = 0; j < 4; ++j) {
                const float x  = x4[k][j];
                const float fg = fg4[j];
                const float e  = __expf(-fabsf(x));     // exp(-|x|)
                const float L  = __logf(1.0f + e);      // log1p(exp(-|x|))
                const float d  = L + fmaxf(-x, 0.0f);   // softplus(x) - x
                const float s  = __expf(-d);            // sigmoid(x)
                aPX[k] += d;
                aX[k]  += x;
                aXF[k]  = fmaf(x, fg, aXF[k]);
                aS[k]  += s;
                aSF[k]  = fmaf(s, fg, aSF[k]);
            }
        }
    }

    // pack 26 block-partial values, reduce per-wave butterfly + LDS combine
    float v[NVAL];
    #pragma unroll
    for (int k = 0; k < KK; ++k) {
        v[k*5+0] = aX[k];  v[k*5+1] = aXF[k]; v[k*5+2] = aS[k];
        v[k*5+3] = aSF[k]; v[k*5+4] = aPX[k];
    }
    v[25] = Tf;

    #pragma unroll
    for (int jv = 0; jv < NVAL; ++jv) {
        float x = v[jv];
        #pragma unroll
        for (int off = 32; off > 0; off >>= 1) x += __shfl_down(x, off, 64);
        v[jv] = x;
    }
    __shared__ float red[THREADS / 64][NVAL];
    const int lane = threadIdx.x & 63;
    const int w    = threadIdx.x >> 6;
    if (lane == 0) {
        #pragma unroll
        for (int jv = 0; jv < NVAL; ++jv) red[w][jv] = v[jv];
    }
    __syncthreads();
    if (threadIdx.x < NVAL) {
        const int jv = threadIdx.x;
        ws[(size_t)bid * REC + jv] =
            red[0][jv] + red[1][jv] + red[2][jv] + red[3][jv];
    }
}

__global__ __launch_bounds__(320) void hung_pass2(const float* __restrict__ ws,
                                                  float* __restrict__ out)
{
    __shared__ float red[BB][KK][6];     // X, XF, S, SF, PX, (Tf at k==0)
    const int t = threadIdx.x;           // t == b*KK + k  (320 threads exactly)
    {
        const int b = t / KK, k = t - (t / KK) * KK;
        float v[5] = {0, 0, 0, 0, 0};
        float tf = 0.f;
        for (int q = 0; q < Q; ++q) {
            const float* p = ws + (size_t)(b * Q + q) * REC;
            #pragma unroll
            for (int c = 0; c < 5; ++c) v[c] += p[k * 5 + c];
            if (k == 0) tf += p[25];
        }
        #pragma unroll
        for (int c = 0; c < 5; ++c) red[b][k][c] = v[c];
        if (k == 0) red[b][0][5] = tf;
    }
    __syncthreads();
    if (t < BB) {                        // wave 0: one image per lane
        const int b = t;
        const float Tf = red[b][0][5];
        const float Tb = (float)NPIX - Tf;
        float best = 3.402823466e+38f; int kb = 0;
        float xfsum = 0.f, px = 0.f;
        #pragma unroll
        for (int k = 0; k < KK; ++k) {
            const float Sv = red[b][k][2], Iv = red[b][k][3];  // S_k, inter_fg
            const float cf = 1.f - Iv / (Sv + Tf - Iv + 1e-6f);
            const float Ib = Sv - Iv;
            const float cb = 1.f - Ib / (Sv + Tb - Ib + 1e-6f);
            const float dd = cf - cb;
            if (dd < best) { best = dd; kb = k; }  // strict < : ties -> smallest k
            xfsum += red[b][k][1];
            px    += red[b][k][4];
        }
        float res = px + xfsum - (2.f * red[b][kb][1] - red[b][kb][0]);  // - C_{k*}
        #pragma unroll
        for (int off = 32; off > 0; off >>= 1) res += __shfl_down(res, off, 64);
        if (b == 0) out[0] = res * (1.0f / 32768000.0f);   // / (B*K*N)
    }
}

extern "C" void kernel_launch(void* const* d_in, const int* in_sizes, int n_in,
                              void* d_out, int out_size, void* d_ws, size_t ws_size,
                              hipStream_t stream) {
    // setup_inputs order: fg_logits (unused by reference!), slot_logits, target
    const float* slot = (const float*)d_in[1];
    const float* tgt  = (const float*)d_in[2];
    float* out = (float*)d_out;
    float* ws  = (float*)d_ws;

    hung_pass1<<<NBLK, THREADS, 0, stream>>>(slot, tgt, ws);
    hung_pass2<<<1, 320, 0, stream>>>(ws, out);
}